// Round 1
// baseline (2628.235 us; speedup 1.0000x reference)
//
#include <hip/hip_runtime.h>
#include <cstddef>
#include <cstdint>

#define N_  4
#define C_  256
#define CC_ 256
#define L_  4096
#define T_  512
#define KS_ 5
#define NL_ 6

#define BM 64
#define BN 64
#define BK 16

// ---------------- time bias: bias[n,c] = sum_t swish(te[n,t]) * tw[c,t] + tb[c]
__global__ __launch_bounds__(128) void time_bias_kernel(
    const float* __restrict__ te, const float* __restrict__ tw,
    const float* __restrict__ tb, float* __restrict__ bias)
{
    int nc = blockIdx.x;
    int n = nc >> 8, c = nc & 255;
    int tid = threadIdx.x;
    float s = 0.f;
    for (int t = tid; t < T_; t += 128) {
        float e = te[n * T_ + t];
        float sw = e / (1.f + expf(-e));
        s += sw * tw[c * T_ + t];
    }
    __shared__ float red[128];
    red[tid] = s;
    __syncthreads();
    for (int off = 64; off > 0; off >>= 1) {
        if (tid < off) red[tid] += red[tid + off];
        __syncthreads();
    }
    if (tid == 0) bias[nc] = red[0] + tb[c];
}

// ---------------- transpose [n][c][l] -> [n][l][c], optional per-(n,c) bias add
__global__ __launch_bounds__(256) void transpose_in_kernel(
    const float* __restrict__ in, const float* __restrict__ bias, float* __restrict__ out)
{
    __shared__ float tile[32][33];
    const int n = blockIdx.z;
    const int l0 = blockIdx.x * 32, c0 = blockIdx.y * 32;
    const int tx = threadIdx.x, ty = threadIdx.y;
    #pragma unroll
    for (int i = 0; i < 4; i++) {
        int c = c0 + ty + 8 * i;
        tile[ty + 8 * i][tx] = in[((size_t)n * C_ + c) * L_ + l0 + tx];
    }
    __syncthreads();
    #pragma unroll
    for (int i = 0; i < 4; i++) {
        int l = l0 + ty + 8 * i;
        int c = c0 + tx;
        float v = tile[tx][ty + 8 * i];
        if (bias) v += bias[n * C_ + c];
        out[((size_t)n * L_ + l) * C_ + c] = v;
    }
}

// ---------------- transpose [n][l][c] -> [n][c][l]
__global__ __launch_bounds__(256) void transpose_out_kernel(
    const float* __restrict__ in, float* __restrict__ out)
{
    __shared__ float tile[32][33];
    const int n = blockIdx.z;
    const int l0 = blockIdx.x * 32, c0 = blockIdx.y * 32;
    const int tx = threadIdx.x, ty = threadIdx.y;
    #pragma unroll
    for (int i = 0; i < 4; i++) {
        int l = l0 + ty + 8 * i;
        tile[ty + 8 * i][tx] = in[((size_t)n * L_ + l) * C_ + c0 + tx];  // tile[l'][c']
    }
    __syncthreads();
    #pragma unroll
    for (int i = 0; i < 4; i++) {
        int c = c0 + ty + 8 * i;
        out[((size_t)n * C_ + c) * L_ + l0 + tx] = tile[tx][ty + 8 * i];
    }
}

// ---------------- conv weight repack: out[j][o][c] = cw[o][c][j]
__global__ __launch_bounds__(256) void repack_conv_kernel(
    const float* __restrict__ cw, float* __restrict__ out)
{
    int idx = blockIdx.x * 256 + threadIdx.x;
    if (idx >= KS_ * C_ * C_) return;
    int j = idx / (C_ * C_);
    int rem = idx % (C_ * C_);
    int o = rem / C_, c = rem % C_;
    out[idx] = cw[(o * C_ + c) * KS_ + j];
}

// ---------------- pointwise GEMM: D[n][l][o] = act(bias[o] + sum parts A_p[l][:].W_p[o][:])
// A layout [N][L][C_], W row-major with given row stride.
template <int RELU, int ACCUM>
__global__ __launch_bounds__(256) void gemm_pw_kernel(
    const float* __restrict__ A1, const float* __restrict__ W1, int w1s,
    const float* __restrict__ A2, const float* __restrict__ W2, int w2s,
    const float* __restrict__ bias, float* __restrict__ D)
{
    __shared__ float As[BK][BM];
    __shared__ float Ws[BK][BN];
    const int n = blockIdx.z;
    const int l0 = blockIdx.x * BM;
    const int o0 = blockIdx.y * BN;
    const int tid = threadIdx.x;
    const int tn = (tid & 15) * 4;   // o within tile (lane-consecutive for coalesced store)
    const int tm = (tid >> 4) * 4;   // l within tile
    const int ar = tid >> 2;         // staging row (0..63)
    const int ac = (tid & 3) * 4;    // staging col (0..12 step 4)
    float acc[4][4] = {};
    for (int part = 0; part < 2; part++) {
        const float* A = part ? A2 : A1;
        const float* W = part ? W2 : W1;
        const int wstride = part ? w2s : w1s;
        if (A == nullptr) break;
        const float* Ab = A + ((size_t)n * L_ + l0) * C_;
        for (int kb = 0; kb < C_; kb += BK) {
            const float4 av = *(const float4*)(Ab + (size_t)ar * C_ + kb + ac);
            const float4 wv = *(const float4*)(W + (size_t)(o0 + ar) * wstride + kb + ac);
            As[ac + 0][ar] = av.x; As[ac + 1][ar] = av.y;
            As[ac + 2][ar] = av.z; As[ac + 3][ar] = av.w;
            Ws[ac + 0][ar] = wv.x; Ws[ac + 1][ar] = wv.y;
            Ws[ac + 2][ar] = wv.z; Ws[ac + 3][ar] = wv.w;
            __syncthreads();
            #pragma unroll
            for (int kk = 0; kk < BK; kk++) {
                const float4 a = *(const float4*)(&As[kk][tm]);
                const float4 b = *(const float4*)(&Ws[kk][tn]);
                const float am[4] = {a.x, a.y, a.z, a.w};
                const float bn[4] = {b.x, b.y, b.z, b.w};
                #pragma unroll
                for (int ii = 0; ii < 4; ii++)
                    #pragma unroll
                    for (int jj = 0; jj < 4; jj++)
                        acc[ii][jj] += am[ii] * bn[jj];
            }
            __syncthreads();
        }
    }
    #pragma unroll
    for (int ii = 0; ii < 4; ii++) {
        const int l = l0 + tm + ii;
        float* drow = D + ((size_t)n * L_ + l) * C_ + o0 + tn;
        #pragma unroll
        for (int jj = 0; jj < 4; jj++) {
            float v2 = acc[ii][jj] + bias[o0 + tn + jj];
            if (RELU) v2 = fmaxf(v2, 0.f);
            if (ACCUM) v2 += drow[jj];
            drow[jj] = v2;
        }
    }
}

// ---------------- dilated conv GEMM: 5 shifted taps over repacked weights [j][o][c]
__global__ __launch_bounds__(256) void gemm_conv_kernel(
    const float* __restrict__ A, const float* __restrict__ Wr,
    const float* __restrict__ bias, float* __restrict__ D, int d)
{
    __shared__ float As[BK][BM];
    __shared__ float Ws[BK][BN];
    const int n = blockIdx.z;
    const int l0 = blockIdx.x * BM;
    const int o0 = blockIdx.y * BN;
    const int tid = threadIdx.x;
    const int tn = (tid & 15) * 4;
    const int tm = (tid >> 4) * 4;
    const int ar = tid >> 2;
    const int ac = (tid & 3) * 4;
    float acc[4][4] = {};
    for (int j = 0; j < KS_; j++) {
        const int shift = (j - 2) * d;
        const float* Wj = Wr + (size_t)j * C_ * C_;
        const int la = l0 + ar + shift;
        const bool inb = (la >= 0 && la < L_);
        const float* Arow = A + ((size_t)n * L_ + la) * C_;
        for (int kb = 0; kb < C_; kb += BK) {
            float4 av = make_float4(0.f, 0.f, 0.f, 0.f);
            if (inb) av = *(const float4*)(Arow + kb + ac);
            const float4 wv = *(const float4*)(Wj + (size_t)(o0 + ar) * C_ + kb + ac);
            As[ac + 0][ar] = av.x; As[ac + 1][ar] = av.y;
            As[ac + 2][ar] = av.z; As[ac + 3][ar] = av.w;
            Ws[ac + 0][ar] = wv.x; Ws[ac + 1][ar] = wv.y;
            Ws[ac + 2][ar] = wv.z; Ws[ac + 3][ar] = wv.w;
            __syncthreads();
            #pragma unroll
            for (int kk = 0; kk < BK; kk++) {
                const float4 a = *(const float4*)(&As[kk][tm]);
                const float4 b = *(const float4*)(&Ws[kk][tn]);
                const float am[4] = {a.x, a.y, a.z, a.w};
                const float bn[4] = {b.x, b.y, b.z, b.w};
                #pragma unroll
                for (int ii = 0; ii < 4; ii++)
                    #pragma unroll
                    for (int jj = 0; jj < 4; jj++)
                        acc[ii][jj] += am[ii] * bn[jj];
            }
            __syncthreads();
        }
    }
    #pragma unroll
    for (int ii = 0; ii < 4; ii++) {
        const int l = l0 + tm + ii;
        float* drow = D + ((size_t)n * L_ + l) * C_ + o0 + tn;
        #pragma unroll
        for (int jj = 0; jj < 4; jj++)
            drow[jj] = acc[ii][jj] + bias[o0 + tn + jj];
    }
}

// ---------------- windowed attention; h += r, exact reference mask semantics
__global__ __launch_bounds__(256) void attn_kernel(
    const float* __restrict__ q, const float* __restrict__ k,
    const float* __restrict__ v, float* __restrict__ h, int d)
{
    const int n = blockIdx.y;
    const int wave = threadIdx.x >> 6;
    const int lane = threadIdx.x & 63;
    const int l = blockIdx.x * 4 + wave;
    const float4 qv = *(const float4*)(q + ((size_t)n * L_ + l) * C_ + lane * 4);
    float att[KS_];
    #pragma unroll
    for (int j = 0; j < KS_; j++) {
        const int lp = l + (j - 2) * d;
        float s = 0.f;
        if (lp >= 0 && lp < L_) {
            const float4 kv = *(const float4*)(k + ((size_t)n * L_ + lp) * C_ + lane * 4);
            s = qv.x * kv.x + qv.y * kv.y + qv.z * kv.z + qv.w * kv.w;
        }
        #pragma unroll
        for (int off = 32; off > 0; off >>= 1) s += __shfl_xor(s, off, 64);
        att[j] = s * 0.0625f;  // / sqrt(256)
    }
    float logit[KS_];
    float m = -1e30f;
    #pragma unroll
    for (int j = 0; j < KS_; j++) {
        const int lp = l + (j - 2) * d;
        const bool valid = (lp >= 0 && lp < L_);
        logit[j] = att[j] + logf((valid ? 1.f : 0.f) + 1e-6f);
        m = fmaxf(m, logit[j]);
    }
    float den = 0.f, wgt[KS_];
    #pragma unroll
    for (int j = 0; j < KS_; j++) { wgt[j] = expf(logit[j] - m); den += wgt[j]; }
    const float inv = 1.f / den;
    float4 r = {0.f, 0.f, 0.f, 0.f};
    #pragma unroll
    for (int j = 0; j < KS_; j++) {
        const int lp = l + (j - 2) * d;
        if (lp < 0 || lp >= L_) continue;  // post-softmax mask multiply
        const float wj = wgt[j] * inv;
        const float4 vv = *(const float4*)(v + ((size_t)n * L_ + lp) * C_ + lane * 4);
        r.x += wj * vv.x; r.y += wj * vv.y; r.z += wj * vv.z; r.w += wj * vv.w;
    }
    float* hrow = h + ((size_t)n * L_ + l) * C_ + lane * 4;
    float4 hv = *(const float4*)hrow;
    hv.x += r.x; hv.y += r.y; hv.z += r.z; hv.w += r.w;
    *(float4*)hrow = hv;
}

// ---------------- instance norm (over l per (n,c)): partial sums
__global__ __launch_bounds__(256) void norm_part_kernel(
    const float* __restrict__ h, float* __restrict__ psum, float* __restrict__ psq)
{
    const int n = blockIdx.y, chunk = blockIdx.x, c = threadIdx.x;
    float s = 0.f, ss = 0.f;
    const int lbase = chunk * (L_ / 16);
    for (int i = 0; i < L_ / 16; i++) {
        const float x = h[((size_t)n * L_ + lbase + i) * C_ + c];
        s += x;
        ss += x * x;
    }
    psum[(n * 16 + chunk) * C_ + c] = s;
    psq[(n * 16 + chunk) * C_ + c] = ss;
}

__global__ __launch_bounds__(256) void norm_fin_kernel(
    const float* __restrict__ psum, const float* __restrict__ psq,
    float* __restrict__ mu, float* __restrict__ sc)
{
    const int idx = blockIdx.x * 256 + threadIdx.x;
    const int n = idx >> 8, c = idx & 255;
    float s = 0.f, ss = 0.f;
    for (int ch = 0; ch < 16; ch++) {
        s += psum[(n * 16 + ch) * C_ + c];
        ss += psq[(n * 16 + ch) * C_ + c];
    }
    const float m = s * (1.f / L_);
    const float var = ss * (1.f / L_) - m * m;  // biased, matches jnp.var
    mu[idx] = m;
    sc[idx] = rsqrtf(var + 1e-5f);
}

__global__ __launch_bounds__(256) void norm_apply_kernel(
    float* __restrict__ h, const float* __restrict__ mu, const float* __restrict__ sc)
{
    const size_t idx = ((size_t)blockIdx.x * 256 + threadIdx.x) * 4;
    const int c = (int)(idx & (C_ - 1));
    const int n = (int)(idx / ((size_t)L_ * C_));
    float4 hv = *(float4*)(h + idx);
    const int b = n * C_ + c;
    hv.x = (hv.x - mu[b + 0]) * sc[b + 0];
    hv.y = (hv.y - mu[b + 1]) * sc[b + 1];
    hv.z = (hv.z - mu[b + 2]) * sc[b + 2];
    hv.w = (hv.w - mu[b + 3]) * sc[b + 3];
    *(float4*)(h + idx) = hv;
}

extern "C" void kernel_launch(void* const* d_in, const int* in_sizes, int n_in,
                              void* d_out, int out_size, void* d_ws, size_t ws_size,
                              hipStream_t stream)
{
    (void)in_sizes; (void)n_in; (void)out_size; (void)ws_size;
    const float* x   = (const float*)d_in[0];
    const float* xc  = (const float*)d_in[1];
    const float* te  = (const float*)d_in[2];
    const float* tw  = (const float*)d_in[3];
    const float* tb  = (const float*)d_in[4];
    const float* cw  = (const float*)d_in[5];
    const float* cb  = (const float*)d_in[6];
    const float* qw  = (const float*)d_in[7];
    const float* qbi = (const float*)d_in[8];
    const float* kw  = (const float*)d_in[9];
    const float* kbi = (const float*)d_in[10];
    const float* vw  = (const float*)d_in[11];
    const float* vbi = (const float*)d_in[12];
    const float* f1w = (const float*)d_in[13];
    const float* f1b = (const float*)d_in[14];
    const float* f2w = (const float*)d_in[15];
    const float* f2b = (const float*)d_in[16];

    float* ws = (float*)d_ws;
    const size_t NLC = (size_t)N_ * L_ * C_;
    float* xT    = ws;
    float* xcT   = xT + NLC;
    float* hb    = xcT + NLC;
    float* qbuf  = hb + NLC;
    float* kbuf  = qbuf + NLC;
    float* vbuf  = kbuf + NLC;
    float* convr = vbuf + NLC;
    float* biasb = convr + (size_t)KS_ * C_ * C_;
    float* mub   = biasb + N_ * C_;
    float* scb   = mub + N_ * C_;
    float* psum  = scb + N_ * C_;
    float* psq   = psum + (size_t)N_ * 16 * C_;

    time_bias_kernel<<<N_ * C_, 128, 0, stream>>>(te, tw, tb, biasb);
    dim3 tgrid(L_ / 32, C_ / 32, N_), tblk(32, 8);
    transpose_in_kernel<<<tgrid, tblk, 0, stream>>>(x, biasb, xT);
    transpose_in_kernel<<<tgrid, tblk, 0, stream>>>(xc, nullptr, xcT);

    dim3 ggrid(L_ / BM, C_ / BN, N_);
    for (int i = 0; i < NL_; i++) {
        const int d = 1 << i;
        const float* cwi  = cw + (size_t)i * C_ * C_ * KS_;
        const float* qwi  = qw + (size_t)i * C_ * (C_ + CC_);
        const float* kwi  = kw + (size_t)i * C_ * (C_ + CC_);
        const float* vwi  = vw + (size_t)i * C_ * C_;
        const float* f1wi = f1w + (size_t)i * C_ * C_;
        const float* f2wi = f2w + (size_t)i * C_ * C_;

        repack_conv_kernel<<<(KS_ * C_ * C_) / 256, 256, 0, stream>>>(cwi, convr);
        gemm_conv_kernel<<<ggrid, 256, 0, stream>>>(xT, convr, cb + i * C_, hb, d);
        gemm_pw_kernel<0, 0><<<ggrid, 256, 0, stream>>>(
            xT, qwi, C_ + CC_, xcT, qwi + C_, C_ + CC_, qbi + i * C_, qbuf);
        gemm_pw_kernel<0, 0><<<ggrid, 256, 0, stream>>>(
            xT, kwi, C_ + CC_, xcT, kwi + C_, C_ + CC_, kbi + i * C_, kbuf);
        gemm_pw_kernel<0, 0><<<ggrid, 256, 0, stream>>>(
            xT, vwi, C_, nullptr, nullptr, 0, vbi + i * C_, vbuf);
        attn_kernel<<<dim3(L_ / 4, N_), 256, 0, stream>>>(qbuf, kbuf, vbuf, hb, d);
        norm_part_kernel<<<dim3(16, N_), 256, 0, stream>>>(hb, psum, psq);
        norm_fin_kernel<<<(N_ * C_) / 256, 256, 0, stream>>>(psum, psq, mub, scb);
        norm_apply_kernel<<<(int)(NLC / 4 / 256), 256, 0, stream>>>(hb, mub, scb);
        gemm_pw_kernel<1, 0><<<ggrid, 256, 0, stream>>>(
            hb, f1wi, C_, nullptr, nullptr, 0, f1b + i * C_, qbuf);
        gemm_pw_kernel<0, 1><<<ggrid, 256, 0, stream>>>(
            qbuf, f2wi, C_, nullptr, nullptr, 0, f2b + i * C_, xT);
    }
    transpose_out_kernel<<<tgrid, tblk, 0, stream>>>(xT, (float*)d_out);
}

// Round 2
// 665.047 us; speedup vs baseline: 3.9520x; 3.9520x over previous
//
#include <hip/hip_runtime.h>
#include <hip/hip_bf16.h>
#include <cstddef>
#include <cstdint>

#define N_   4
#define C_   256
#define L_   4096
#define T_   512
#define KS_  5
#define NL_  6
#define HALO 64
#define LP_  (L_ + 2 * HALO)   // 4224 padded rows per n in xcat
#define XCS  512               // xcat row stride: [x(256) | x_cross(256)]

typedef __attribute__((ext_vector_type(8))) __bf16 bf16x8;
typedef __attribute__((ext_vector_type(4))) float f32x4;

__device__ __forceinline__ void gload_lds16(const void* g, void* l) {
    __builtin_amdgcn_global_load_lds(
        (const __attribute__((address_space(1))) unsigned int*)g,
        (__attribute__((address_space(3))) unsigned int*)l, 16, 0, 0);
}
__device__ __forceinline__ float bf2f(unsigned short u) {
    union { unsigned int i; float f; } x; x.i = ((unsigned int)u) << 16; return x.f;
}
__device__ __forceinline__ unsigned short f2bf(float f) {
    __hip_bfloat16 h = __float2bfloat16(f);
    return *reinterpret_cast<unsigned short*>(&h);
}
__device__ __forceinline__ float4 ld4bf(const unsigned short* p) {
    ushort4 u = *reinterpret_cast<const ushort4*>(p);
    return make_float4(bf2f(u.x), bf2f(u.y), bf2f(u.z), bf2f(u.w));
}

// =================== MFMA GEMM, m97 structure: 128x128 tile, BK=32 ===================
// D[r][o] = sum_k A[r][k] * B[o][k]; A rows mapped through (n,l)->padded pitch.
// EP: 0 = fp32 out (+bias)   1 = bf16 out (+bias)   2 = bf16 relu out   3 = residual
template <int EP>
__global__ __launch_bounds__(256) void gemm_std(
    const unsigned short* __restrict__ A, int apitch, int apad, int astride,
    const unsigned short* __restrict__ B, int bstride, int K,
    const float* __restrict__ bias, int OC,
    float* __restrict__ outf, unsigned short* __restrict__ outb,
    float* __restrict__ xres, unsigned short* __restrict__ xcat)
{
    __shared__ alignas(16) unsigned short As[128 * 32];
    __shared__ alignas(16) unsigned short Bs[128 * 32];
    const int tid = threadIdx.x;
    const int wid = tid >> 6, lane = tid & 63;
    const int wr = wid >> 1, wc = wid & 1;
    const int r0 = blockIdx.x * 128;
    const int o0 = blockIdx.y * 128;
    const int n = r0 >> 12, lb = r0 & (L_ - 1);
    const size_t abase = ((size_t)n * apitch + apad + lb) * astride;
    const int s0 = wid * 64 + lane;  // staging slot, issue 0; +256 for issue 1
    f32x4 acc[4][4] = {};
    for (int kb = 0; kb < K; kb += 32) {
        #pragma unroll
        for (int i = 0; i < 2; i++) {
            const int s = s0 + i * 256;
            const int row = s >> 2, seg = s & 3;
            gload_lds16(A + abase + (size_t)row * astride + kb + seg * 8, As + s * 8);
            gload_lds16(B + (size_t)(o0 + row) * bstride + kb + seg * 8, Bs + s * 8);
        }
        __syncthreads();
        const int rsel = lane & 15, ksel = (lane >> 4) * 8;
        bf16x8 af[4], bf[4];
        #pragma unroll
        for (int m = 0; m < 4; m++)
            af[m] = *reinterpret_cast<const bf16x8*>(&As[(wr * 64 + m * 16 + rsel) * 32 + ksel]);
        #pragma unroll
        for (int nn = 0; nn < 4; nn++)
            bf[nn] = *reinterpret_cast<const bf16x8*>(&Bs[(wc * 64 + nn * 16 + rsel) * 32 + ksel]);
        #pragma unroll
        for (int m = 0; m < 4; m++)
            #pragma unroll
            for (int nn = 0; nn < 4; nn++)
                acc[m][nn] = __builtin_amdgcn_mfma_f32_16x16x32_bf16(af[m], bf[nn], acc[m][nn], 0, 0, 0);
        __syncthreads();
    }
    const int orow = (lane >> 4) * 4, ocol = lane & 15;
    #pragma unroll
    for (int m = 0; m < 4; m++) {
        #pragma unroll
        for (int nn = 0; nn < 4; nn++) {
            const int gr0 = r0 + wr * 64 + m * 16 + orow;
            const int gc = o0 + wc * 64 + nn * 16 + ocol;
            const float bv = bias[gc];
            #pragma unroll
            for (int rr = 0; rr < 4; rr++) {
                const int gr = gr0 + rr;
                const float v = acc[m][nn][rr] + bv;
                if (EP == 0) {
                    outf[(size_t)gr * OC + gc] = v;
                } else if (EP == 1) {
                    outb[(size_t)gr * OC + gc] = f2bf(v);
                } else if (EP == 2) {
                    outb[(size_t)gr * OC + gc] = f2bf(fmaxf(v, 0.f));
                } else {
                    const float nv = v + xres[(size_t)gr * C_ + gc];
                    xres[(size_t)gr * C_ + gc] = nv;
                    const int n2 = gr >> 12, ll = gr & (L_ - 1);
                    xcat[((size_t)n2 * LP_ + HALO + ll) * XCS + gc] = f2bf(nv);
                }
            }
        }
    }
}

// =================== conv GEMM: 5 dilated taps, A = xcat (zero halo) ===================
__global__ __launch_bounds__(256) void gemm_conv(
    const unsigned short* __restrict__ A,   // xcat
    const unsigned short* __restrict__ W,   // [5][256][256] bf16
    const float* __restrict__ bias, float* __restrict__ outf, int d)
{
    __shared__ alignas(16) unsigned short As[128 * 32];
    __shared__ alignas(16) unsigned short Bs[128 * 32];
    const int tid = threadIdx.x;
    const int wid = tid >> 6, lane = tid & 63;
    const int wr = wid >> 1, wc = wid & 1;
    const int r0 = blockIdx.x * 128;
    const int o0 = blockIdx.y * 128;
    const int n = r0 >> 12, lb = r0 & (L_ - 1);
    const int s0 = wid * 64 + lane;
    f32x4 acc[4][4] = {};
    for (int j = 0; j < KS_; j++) {
        const size_t abase = (size_t)((long)n * LP_ + HALO + lb + (j - 2) * d) * XCS;
        const unsigned short* Wj = W + (size_t)j * C_ * C_;
        for (int kb = 0; kb < C_; kb += 32) {
            #pragma unroll
            for (int i = 0; i < 2; i++) {
                const int s = s0 + i * 256;
                const int row = s >> 2, seg = s & 3;
                gload_lds16(A + abase + (size_t)row * XCS + kb + seg * 8, As + s * 8);
                gload_lds16(Wj + (size_t)(o0 + row) * C_ + kb + seg * 8, Bs + s * 8);
            }
            __syncthreads();
            const int rsel = lane & 15, ksel = (lane >> 4) * 8;
            bf16x8 af[4], bf[4];
            #pragma unroll
            for (int m = 0; m < 4; m++)
                af[m] = *reinterpret_cast<const bf16x8*>(&As[(wr * 64 + m * 16 + rsel) * 32 + ksel]);
            #pragma unroll
            for (int nn = 0; nn < 4; nn++)
                bf[nn] = *reinterpret_cast<const bf16x8*>(&Bs[(wc * 64 + nn * 16 + rsel) * 32 + ksel]);
            #pragma unroll
            for (int m = 0; m < 4; m++)
                #pragma unroll
                for (int nn = 0; nn < 4; nn++)
                    acc[m][nn] = __builtin_amdgcn_mfma_f32_16x16x32_bf16(af[m], bf[nn], acc[m][nn], 0, 0, 0);
            __syncthreads();
        }
    }
    const int orow = (lane >> 4) * 4, ocol = lane & 15;
    #pragma unroll
    for (int m = 0; m < 4; m++) {
        #pragma unroll
        for (int nn = 0; nn < 4; nn++) {
            const int gr0 = r0 + wr * 64 + m * 16 + orow;
            const int gc = o0 + wc * 64 + nn * 16 + ocol;
            const float bv = bias[gc];
            #pragma unroll
            for (int rr = 0; rr < 4; rr++)
                outf[(size_t)(gr0 + rr) * C_ + gc] = acc[m][nn][rr] + bv;
        }
    }
}

// =================== time bias ===================
__global__ __launch_bounds__(128) void time_bias_kernel(
    const float* __restrict__ te, const float* __restrict__ tw,
    const float* __restrict__ tb, float* __restrict__ bias)
{
    int nc = blockIdx.x;
    int n = nc >> 8, c = nc & 255;
    int tid = threadIdx.x;
    float s = 0.f;
    for (int t = tid; t < T_; t += 128) {
        float e = te[n * T_ + t];
        s += (e / (1.f + expf(-e))) * tw[c * T_ + t];
    }
    __shared__ float red[128];
    red[tid] = s;
    __syncthreads();
    for (int off = 64; off > 0; off >>= 1) {
        if (tid < off) red[tid] += red[tid + off];
        __syncthreads();
    }
    if (tid == 0) bias[nc] = red[0] + tb[c];
}

// =================== transpose in: [n][c][l] -> xres fp32 / xcat bf16 ===================
template <int MODE>  // 0: x (+bias -> xres & xcat cols 0-255), 1: xc (-> xcat cols 256-511)
__global__ __launch_bounds__(256) void transpose_in(
    const float* __restrict__ in, const float* __restrict__ bias,
    float* __restrict__ xres, unsigned short* __restrict__ xcat)
{
    __shared__ float tile[32][33];
    const int n = blockIdx.z;
    const int l0 = blockIdx.x * 32, c0 = blockIdx.y * 32;
    const int tx = threadIdx.x, ty = threadIdx.y;
    #pragma unroll
    for (int i = 0; i < 4; i++) {
        int c = c0 + ty + 8 * i;
        tile[ty + 8 * i][tx] = in[((size_t)n * C_ + c) * L_ + l0 + tx];
    }
    __syncthreads();
    #pragma unroll
    for (int i = 0; i < 4; i++) {
        const int l = l0 + ty + 8 * i;
        const int c = c0 + tx;
        float v = tile[tx][ty + 8 * i];
        if (MODE == 0) {
            v += bias[n * C_ + c];
            xres[((size_t)n * L_ + l) * C_ + c] = v;
            xcat[((size_t)n * LP_ + HALO + l) * XCS + c] = f2bf(v);
        } else {
            xcat[((size_t)n * LP_ + HALO + l) * XCS + C_ + c] = f2bf(v);
        }
    }
}

// =================== transpose out: xres [n][l][c] -> [n][c][l] ===================
__global__ __launch_bounds__(256) void transpose_out(
    const float* __restrict__ in, float* __restrict__ out)
{
    __shared__ float tile[32][33];
    const int n = blockIdx.z;
    const int l0 = blockIdx.x * 32, c0 = blockIdx.y * 32;
    const int tx = threadIdx.x, ty = threadIdx.y;
    #pragma unroll
    for (int i = 0; i < 4; i++) {
        int l = l0 + ty + 8 * i;
        tile[ty + 8 * i][tx] = in[((size_t)n * L_ + l) * C_ + c0 + tx];
    }
    __syncthreads();
    #pragma unroll
    for (int i = 0; i < 4; i++) {
        int c = c0 + ty + 8 * i;
        out[((size_t)n * C_ + c) * L_ + l0 + tx] = tile[tx][ty + 8 * i];
    }
}

// =================== weight prep ===================
__global__ __launch_bounds__(256) void prep_qkv(
    const float* __restrict__ qw, const float* __restrict__ kw, const float* __restrict__ vw,
    const float* __restrict__ qb, const float* __restrict__ kb, const float* __restrict__ vb,
    unsigned short* __restrict__ W, float* __restrict__ Bias)
{
    const size_t idx = (size_t)blockIdx.x * 256 + threadIdx.x;
    const int layer = (int)(idx / (768 * 512));
    const int rem = (int)(idx % (768 * 512));
    const int row = rem >> 9, k = rem & 511;
    float v;
    if (row < 256) v = qw[((size_t)layer * 256 + row) * 512 + k];
    else if (row < 512) v = kw[((size_t)layer * 256 + row - 256) * 512 + k];
    else v = (k < 256) ? vw[((size_t)layer * 256 + row - 512) * 256 + k] : 0.f;
    W[idx] = f2bf(v);
    if (k == 0) {
        float b;
        if (row < 256) b = qb[layer * 256 + row];
        else if (row < 512) b = kb[layer * 256 + row - 256];
        else b = vb[layer * 256 + row - 512];
        Bias[layer * 768 + row] = b;
    }
}

__global__ __launch_bounds__(256) void prep_conv(
    const float* __restrict__ cw, unsigned short* __restrict__ W)
{
    const size_t idx = (size_t)blockIdx.x * 256 + threadIdx.x;
    const int layer = (int)(idx / (KS_ * C_ * C_));
    const int rem = (int)(idx % (KS_ * C_ * C_));
    const int j = rem / (C_ * C_);
    const int o = (rem / C_) & 255, c = rem & 255;
    W[idx] = f2bf(cw[(((size_t)layer * C_ + o) * C_ + c) * KS_ + j]);
}

__global__ __launch_bounds__(256) void conv_f2bf(
    const float* __restrict__ in, unsigned short* __restrict__ out, int nelem)
{
    const int idx = blockIdx.x * 256 + threadIdx.x;
    if (idx < nelem) out[idx] = f2bf(in[idx]);
}

// =================== attention (window KS=5), h += r ===================
__global__ __launch_bounds__(256) void attn_kernel(
    const unsigned short* __restrict__ qkv, float* __restrict__ h, int d)
{
    const int n = blockIdx.y;
    const int wave = threadIdx.x >> 6;
    const int lane = threadIdx.x & 63;
    const int l = blockIdx.x * 4 + wave;
    const float4 qv = ld4bf(qkv + ((size_t)n * L_ + l) * 768 + lane * 4);
    float att[KS_];
    #pragma unroll
    for (int j = 0; j < KS_; j++) {
        const int lp = l + (j - 2) * d;
        float s = 0.f;
        if (lp >= 0 && lp < L_) {
            const float4 kv = ld4bf(qkv + ((size_t)n * L_ + lp) * 768 + 256 + lane * 4);
            s = qv.x * kv.x + qv.y * kv.y + qv.z * kv.z + qv.w * kv.w;
        }
        #pragma unroll
        for (int off = 32; off > 0; off >>= 1) s += __shfl_xor(s, off, 64);
        att[j] = s * 0.0625f;
    }
    float logit[KS_], m = -1e30f;
    #pragma unroll
    for (int j = 0; j < KS_; j++) {
        const int lp = l + (j - 2) * d;
        logit[j] = att[j] + logf(((lp >= 0 && lp < L_) ? 1.f : 0.f) + 1e-6f);
        m = fmaxf(m, logit[j]);
    }
    float den = 0.f, wgt[KS_];
    #pragma unroll
    for (int j = 0; j < KS_; j++) { wgt[j] = expf(logit[j] - m); den += wgt[j]; }
    const float inv = 1.f / den;
    float4 r = {0.f, 0.f, 0.f, 0.f};
    #pragma unroll
    for (int j = 0; j < KS_; j++) {
        const int lp = l + (j - 2) * d;
        if (lp < 0 || lp >= L_) continue;
        const float wj = wgt[j] * inv;
        const float4 vv = ld4bf(qkv + ((size_t)n * L_ + lp) * 768 + 512 + lane * 4);
        r.x += wj * vv.x; r.y += wj * vv.y; r.z += wj * vv.z; r.w += wj * vv.w;
    }
    float* hrow = h + ((size_t)n * L_ + l) * C_ + lane * 4;
    float4 hv = *(const float4*)hrow;
    hv.x += r.x; hv.y += r.y; hv.z += r.z; hv.w += r.w;
    *(float4*)hrow = hv;
}

// =================== instance norm ===================
__global__ __launch_bounds__(256) void norm_part(
    const float* __restrict__ h, float* __restrict__ psum, float* __restrict__ psq)
{
    const int n = blockIdx.y, chunk = blockIdx.x, c = threadIdx.x;
    float s = 0.f, ss = 0.f;
    const int lbase = chunk * (L_ / 16);
    for (int i = 0; i < L_ / 16; i++) {
        const float x = h[((size_t)n * L_ + lbase + i) * C_ + c];
        s += x; ss += x * x;
    }
    psum[(n * 16 + chunk) * C_ + c] = s;
    psq[(n * 16 + chunk) * C_ + c] = ss;
}

__global__ __launch_bounds__(256) void norm_fin(
    const float* __restrict__ psum, const float* __restrict__ psq,
    float* __restrict__ mu, float* __restrict__ sc)
{
    const int idx = blockIdx.x * 256 + threadIdx.x;
    const int n = idx >> 8;
    float s = 0.f, ss = 0.f;
    for (int ch = 0; ch < 16; ch++) {
        s += psum[(n * 16 + ch) * C_ + (idx & 255)];
        ss += psq[(n * 16 + ch) * C_ + (idx & 255)];
    }
    const float m = s * (1.f / L_);
    mu[idx] = m;
    sc[idx] = rsqrtf(ss * (1.f / L_) - m * m + 1e-5f);
}

__global__ __launch_bounds__(256) void norm_apply(
    const float* __restrict__ h, const float* __restrict__ mu,
    const float* __restrict__ sc, unsigned short* __restrict__ hnb)
{
    const size_t idx = ((size_t)blockIdx.x * 256 + threadIdx.x) * 4;
    const int c = (int)(idx & (C_ - 1));
    const int n = (int)(idx / ((size_t)L_ * C_));
    const float4 hv = *(const float4*)(h + idx);
    const int b = n * C_ + c;
    ushort4 o;
    o.x = f2bf((hv.x - mu[b + 0]) * sc[b + 0]);
    o.y = f2bf((hv.y - mu[b + 1]) * sc[b + 1]);
    o.z = f2bf((hv.z - mu[b + 2]) * sc[b + 2]);
    o.w = f2bf((hv.w - mu[b + 3]) * sc[b + 3]);
    *(ushort4*)(hnb + idx) = o;
}

// =================== launch ===================
extern "C" void kernel_launch(void* const* d_in, const int* in_sizes, int n_in,
                              void* d_out, int out_size, void* d_ws, size_t ws_size,
                              hipStream_t stream)
{
    (void)in_sizes; (void)n_in; (void)out_size; (void)ws_size;
    const float* x   = (const float*)d_in[0];
    const float* xc  = (const float*)d_in[1];
    const float* te  = (const float*)d_in[2];
    const float* tw  = (const float*)d_in[3];
    const float* tb  = (const float*)d_in[4];
    const float* cw  = (const float*)d_in[5];
    const float* cb  = (const float*)d_in[6];
    const float* qw  = (const float*)d_in[7];
    const float* qbi = (const float*)d_in[8];
    const float* kw  = (const float*)d_in[9];
    const float* kbi = (const float*)d_in[10];
    const float* vw  = (const float*)d_in[11];
    const float* vbi = (const float*)d_in[12];
    const float* f1w = (const float*)d_in[13];
    const float* f1b = (const float*)d_in[14];
    const float* f2w = (const float*)d_in[15];
    const float* f2b = (const float*)d_in[16];

    char* p = (char*)d_ws;
    auto alloc = [&](size_t bytes) { char* r = p; p += (bytes + 255) & ~(size_t)255; return r; };
    const size_t NLC = (size_t)N_ * L_ * C_;
    float* xres  = (float*)alloc(NLC * 4);
    float* hb    = (float*)alloc(NLC * 4);
    unsigned short* xcat  = (unsigned short*)alloc((size_t)N_ * LP_ * XCS * 2);
    unsigned short* qkvb  = (unsigned short*)alloc((size_t)N_ * L_ * 768 * 2);
    unsigned short* hnb   = (unsigned short*)alloc(NLC * 2);
    unsigned short* f1ob  = (unsigned short*)alloc(NLC * 2);
    unsigned short* wqkvb = (unsigned short*)alloc((size_t)NL_ * 768 * 512 * 2);
    unsigned short* wconvb= (unsigned short*)alloc((size_t)NL_ * KS_ * C_ * C_ * 2);
    unsigned short* wf1b  = (unsigned short*)alloc((size_t)NL_ * C_ * C_ * 2);
    unsigned short* wf2b  = (unsigned short*)alloc((size_t)NL_ * C_ * C_ * 2);
    float* qkvbias = (float*)alloc((size_t)NL_ * 768 * 4);
    float* biasb = (float*)alloc(N_ * C_ * 4);
    float* mub   = (float*)alloc(N_ * C_ * 4);
    float* scb   = (float*)alloc(N_ * C_ * 4);
    float* psum  = (float*)alloc((size_t)N_ * 16 * C_ * 4);
    float* psq   = (float*)alloc((size_t)N_ * 16 * C_ * 4);

    hipMemsetAsync(xcat, 0, (size_t)N_ * LP_ * XCS * 2, stream);

    prep_qkv<<<(NL_ * 768 * 512) / 256, 256, 0, stream>>>(qw, kw, vw, qbi, kbi, vbi, wqkvb, qkvbias);
    prep_conv<<<(NL_ * KS_ * C_ * C_) / 256, 256, 0, stream>>>(cw, wconvb);
    conv_f2bf<<<(NL_ * C_ * C_) / 256, 256, 0, stream>>>(f1w, wf1b, NL_ * C_ * C_);
    conv_f2bf<<<(NL_ * C_ * C_) / 256, 256, 0, stream>>>(f2w, wf2b, NL_ * C_ * C_);

    time_bias_kernel<<<N_ * C_, 128, 0, stream>>>(te, tw, tb, biasb);
    dim3 tgrid(L_ / 32, C_ / 32, N_), tblk(32, 8);
    transpose_in<0><<<tgrid, tblk, 0, stream>>>(x, biasb, xres, xcat);
    transpose_in<1><<<tgrid, tblk, 0, stream>>>(xc, nullptr, nullptr, xcat);

    const dim3 g256(128, 2), g768(128, 6);
    for (int i = 0; i < NL_; i++) {
        const int d = 1 << i;
        gemm_conv<<<g256, 256, 0, stream>>>(
            xcat, wconvb + (size_t)i * KS_ * C_ * C_, cb + i * C_, hb, d);
        gemm_std<1><<<g768, 256, 0, stream>>>(
            xcat, LP_, HALO, XCS, wqkvb + (size_t)i * 768 * 512, 512, 512,
            qkvbias + i * 768, 768, nullptr, qkvb, nullptr, nullptr);
        attn_kernel<<<dim3(L_ / 4, N_), 256, 0, stream>>>(qkvb, hb, d);
        norm_part<<<dim3(16, N_), 256, 0, stream>>>(hb, psum, psq);
        norm_fin<<<(N_ * C_) / 256, 256, 0, stream>>>(psum, psq, mub, scb);
        norm_apply<<<(int)(NLC / 4 / 256), 256, 0, stream>>>(hb, mub, scb, hnb);
        gemm_std<2><<<g256, 256, 0, stream>>>(
            hnb, L_, 0, C_, wf1b + (size_t)i * C_ * C_, C_, C_,
            f1b + i * C_, C_, nullptr, f1ob, nullptr, nullptr);
        gemm_std<3><<<g256, 256, 0, stream>>>(
            f1ob, L_, 0, C_, wf2b + (size_t)i * C_ * C_, C_, C_,
            f2b + i * C_, C_, nullptr, nullptr, xres, xcat);
    }
    transpose_out<<<tgrid, tblk, 0, stream>>>(xres, (float*)d_out);
}